// Round 12
// baseline (79.125 us; speedup 1.0000x reference)
//
#include <hip/hip_runtime.h>
#include <math.h>

#define Bb 64
#define Ll 1024
#define Dd 512
#define Aa 512
#define NEG_INF -1e9f

#define LOG2E  1.4426950408889634f
#define LOG2E2 2.8853901617526703f   // 2*log2(e)

typedef float fx4 __attribute__((ext_vector_type(4)));

__device__ __forceinline__ float fast_exp2(float x) { return __builtin_amdgcn_exp2f(x); }
__device__ __forceinline__ float fast_rcp(float x)  { return __builtin_amdgcn_rcpf(x); }

#define TERMS(ACC, KA, KB, Q0, Q1, V0, V1)                                      \
    ACC = fmaf(V0.x, fast_rcp(fast_exp2(fmaf(KA.x, LOG2E2, Q0.x)) + 1.f), ACC); \
    ACC = fmaf(V0.y, fast_rcp(fast_exp2(fmaf(KA.y, LOG2E2, Q0.y)) + 1.f), ACC); \
    ACC = fmaf(V0.z, fast_rcp(fast_exp2(fmaf(KA.z, LOG2E2, Q0.z)) + 1.f), ACC); \
    ACC = fmaf(V0.w, fast_rcp(fast_exp2(fmaf(KA.w, LOG2E2, Q0.w)) + 1.f), ACC); \
    ACC = fmaf(V1.x, fast_rcp(fast_exp2(fmaf(KB.x, LOG2E2, Q1.x)) + 1.f), ACC); \
    ACC = fmaf(V1.y, fast_rcp(fast_exp2(fmaf(KB.y, LOG2E2, Q1.y)) + 1.f), ACC); \
    ACC = fmaf(V1.z, fast_rcp(fast_exp2(fmaf(KB.z, LOG2E2, Q1.z)) + 1.f), ACC); \
    ACC = fmaf(V1.w, fast_rcp(fast_exp2(fmaf(KB.w, LOG2E2, Q1.w)) + 1.f), ACC);

#define RED6(A)                    \
    A += __shfl_xor(A, 32);        \
    A += __shfl_xor(A, 16);        \
    A += __shfl_xor(A, 8);         \
    A += __shfl_xor(A, 4);         \
    A += __shfl_xor(A, 2);         \
    A += __shfl_xor(A, 1);

// One block per batch row b. 512 threads = 8 waves.
// Phase 1: q = dh@W^T + bias (in-block, once), vv, ec.
// Phase 2: energy + sigmoid -> p in LDS (R6's proven 16-load batch pattern).
// Phase 3: in-block scan (validated k_scan256 body) -> alpha.
__global__ __launch_bounds__(512, 2) void k_all(const float* __restrict__ key,
                                                const float* __restrict__ dh,
                                                const float* __restrict__ W,
                                                const float* __restrict__ bias,
                                                const float* __restrict__ vw,
                                                const float* __restrict__ vg,
                                                const float* __restrict__ vb,
                                                const float* __restrict__ r,
                                                const float* __restrict__ noise,
                                                const float* __restrict__ mask,
                                                const float* __restrict__ prev,
                                                float* __restrict__ alpha) {
    const int b = blockIdx.x;
    const int tid = threadIdx.x;
    const int wave = tid >> 6, lane = tid & 63;

    __shared__ float h[Dd];
    __shared__ float qs[Aa];
    __shared__ float vs[Aa];
    __shared__ float p_lds[Ll];
    __shared__ float redS[8], redT[8];
    __shared__ float pend[4], wA[4], wB[4];

    // ---- phase 1a: h to LDS, vw reductions ----
    h[tid] = dh[(size_t)b * Dd + tid];
    const float vwv = vw[tid];
    {
        float s = vwv * vwv;
        float t = vwv;
        #pragma unroll
        for (int off = 32; off; off >>= 1) {
            s += __shfl_xor(s, off);
            t += __shfl_xor(t, off);
        }
        if (lane == 0) { redS[wave] = s; redT[wave] = t; }
    }
    __syncthreads();
    const float sumsq = redS[0] + redS[1] + redS[2] + redS[3]
                      + redS[4] + redS[5] + redS[6] + redS[7];
    const float sumw  = redT[0] + redT[1] + redT[2] + redT[3]
                      + redT[4] + redT[5] + redT[6] + redT[7];
    const float inv = rsqrtf(sumsq);
    const float g   = vg[0];
    const float g2i = 2.f * g * inv;
    const float ec  = g * inv * sumw + vb[0] + r[0];   // sum(vv) + vbias + r

    // ---- phase 1b: q rows, 8 threads per row, 8 passes ----
    {
        const int rr = tid >> 3;             // row within 64-row pass
        const int e  = tid & 7;              // eighth of the row
        const fx4* h4 = (const fx4*)(h + e * 64);
        fx4 h0 = h4[0], h1 = h4[1], h2 = h4[2], h3 = h4[3];
        fx4 h4v = h4[4], h5 = h4[5], h6 = h4[6], h7 = h4[7];
        fx4 h8 = h4[8], h9 = h4[9], hA = h4[10], hB = h4[11];
        fx4 hC = h4[12], hD = h4[13], hE = h4[14], hF = h4[15];
        #pragma unroll 1
        for (int pass = 0; pass < 8; ++pass) {
            const int arow = pass * 64 + rr;
            const fx4* Wr = (const fx4*)(W + (size_t)arow * Dd + e * 64);
            float acc;
            {
                fx4 w0 = Wr[0], w1 = Wr[1], w2 = Wr[2], w3 = Wr[3];
                fx4 w4 = Wr[4], w5 = Wr[5], w6 = Wr[6], w7 = Wr[7];
                fx4 w8 = Wr[8], w9 = Wr[9], wA_ = Wr[10], wB_ = Wr[11];
                fx4 wC = Wr[12], wD = Wr[13], wE = Wr[14], wF = Wr[15];
                fx4 s = w0 * h0;
                s += w1 * h1;  s += w2 * h2;  s += w3 * h3;
                s += w4 * h4v; s += w5 * h5;  s += w6 * h6;  s += w7 * h7;
                s += w8 * h8;  s += w9 * h9;  s += wA_ * hA; s += wB_ * hB;
                s += wC * hC;  s += wD * hD;  s += wE * hE;  s += wF * hF;
                acc = (s.x + s.y) + (s.z + s.w);
            }
            acc += __shfl_xor(acc, 1);
            acc += __shfl_xor(acc, 2);
            acc += __shfl_xor(acc, 4);
            if (e == 0) {
                qs[arow] = (acc + bias[arow]) * LOG2E2;   // pre-scaled
                vs[arow] = g2i * vw[arow];                // = 2*vv
            }
        }
    }
    __syncthreads();

    // ---- phase 2: energy + sigmoid for all 1024 l, p -> LDS ----
    {
        const fx4* qs4 = (const fx4*)qs;
        const fx4* vs4 = (const fx4*)vs;
        const fx4 q0 = qs4[lane];
        const fx4 q1 = qs4[lane + 64];
        const fx4 v0 = vs4[lane];
        const fx4 v1 = vs4[lane + 64];
        const int lj = lane & 7;

        #pragma unroll 1
        for (int it = 0; it < 16; ++it) {
            const int lw0 = it * 64 + wave * 8;   // this batch's first l
            const int l = lw0 + lj;
            const float mk = mask[(size_t)b * Ll + l];
            const float nz = noise[(size_t)b * Ll + l];
            const float mn = (l == Ll - 1) ? 0.f : mask[(size_t)b * Ll + l + 1];

            const fx4* kp = (const fx4*)(key + ((size_t)b * Ll + lw0) * Aa);
            fx4 ka0 = kp[lane];           fx4 kb0 = kp[lane + 64];
            fx4 ka1 = kp[lane + 128];     fx4 kb1 = kp[lane + 192];
            fx4 ka2 = kp[lane + 256];     fx4 kb2 = kp[lane + 320];
            fx4 ka3 = kp[lane + 384];     fx4 kb3 = kp[lane + 448];
            fx4 ka4 = kp[lane + 512];     fx4 kb4 = kp[lane + 576];
            fx4 ka5 = kp[lane + 640];     fx4 kb5 = kp[lane + 704];
            fx4 ka6 = kp[lane + 768];     fx4 kb6 = kp[lane + 832];
            fx4 ka7 = kp[lane + 896];     fx4 kb7 = kp[lane + 960];
            __builtin_amdgcn_sched_barrier(0);   // loads stay above the compute

            float a0 = 0.f, a1 = 0.f, a2 = 0.f, a3 = 0.f,
                  a4 = 0.f, a5 = 0.f, a6 = 0.f, a7 = 0.f;
            TERMS(a0, ka0, kb0, q0, q1, v0, v1)
            TERMS(a1, ka1, kb1, q0, q1, v0, v1)
            TERMS(a2, ka2, kb2, q0, q1, v0, v1)
            TERMS(a3, ka3, kb3, q0, q1, v0, v1)
            TERMS(a4, ka4, kb4, q0, q1, v0, v1)
            TERMS(a5, ka5, kb5, q0, q1, v0, v1)
            TERMS(a6, ka6, kb6, q0, q1, v0, v1)
            TERMS(a7, ka7, kb7, q0, q1, v0, v1)

            RED6(a0) RED6(a1) RED6(a2) RED6(a3) RED6(a4) RED6(a5) RED6(a6) RED6(a7)

            float sel = a0;
            sel = (lj == 1) ? a1 : sel;
            sel = (lj == 2) ? a2 : sel;
            sel = (lj == 3) ? a3 : sel;
            sel = (lj == 4) ? a4 : sel;
            sel = (lj == 5) ? a5 : sel;
            sel = (lj == 6) ? a6 : sel;
            sel = (lj == 7) ? a7 : sel;

            float e = (mk > 0.f) ? (ec - sel) : NEG_INF;
            float z = e + nz;
            float pv = fast_rcp(1.f + fast_exp2(-z * LOG2E));
            float em = mk * (1.f - mn);
            if (em > 0.f) pv = em;
            if (lane < 8) p_lds[l] = pv;
            __builtin_amdgcn_sched_barrier(0);   // no cross-batch register inflation
        }
    }
    __syncthreads();

    // ---- phase 3: scan (tid < 256, 4 l each) ----
    if (tid < 256) {
        const float4 pp = ((const float4*)p_lds)[tid];
        const float4 pa = ((const float4*)(prev + (size_t)b * Ll))[tid];

        if (lane == 63) pend[wave] = pp.w;
        __syncthreads();
        float pm1 = __shfl_up(pp.w, 1);
        if (lane == 0) pm1 = (wave == 0) ? 0.f : pend[wave - 1];

        const float a0 = 1.f - pm1;
        const float a1 = 1.f - pp.x;
        const float a2 = 1.f - pp.y;
        const float a3 = 1.f - pp.z;

        float A = a0, Bv = pa.x;
        Bv = fmaf(a1, Bv, pa.y); A *= a1;
        Bv = fmaf(a2, Bv, pa.z); A *= a2;
        Bv = fmaf(a3, Bv, pa.w); A *= a3;

        float Ai = A, Bi = Bv;
        #pragma unroll
        for (int off = 1; off < 64; off <<= 1) {
            float qA = __shfl_up(Ai, off);
            float qB = __shfl_up(Bi, off);
            if (lane >= off) { Bi = fmaf(Ai, qB, Bi); Ai *= qA; }
        }
        float eA = __shfl_up(Ai, 1), eB = __shfl_up(Bi, 1);
        if (lane == 0) { eA = 1.f; eB = 0.f; }
        if (lane == 63) { wA[wave] = Ai; wB[wave] = Bi; }
        __syncthreads();
        float bwe = 0.f;
        for (int w2 = 0; w2 < wave; ++w2) bwe = fmaf(wA[w2], bwe, wB[w2]);
        float x = fmaf(eA, bwe, eB);

        float4 o;
        x = fmaf(a0, x, pa.x); o.x = pp.x * x;
        x = fmaf(a1, x, pa.y); o.y = pp.y * x;
        x = fmaf(a2, x, pa.z); o.z = pp.z * x;
        x = fmaf(a3, x, pa.w); o.w = pp.w * x;
        ((float4*)(alpha + (size_t)b * Ll))[tid] = o;
    }
}

extern "C" void kernel_launch(void* const* d_in, const int* in_sizes, int n_in,
                              void* d_out, int out_size, void* d_ws, size_t ws_size,
                              hipStream_t stream) {
    const float* dh    = (const float*)d_in[0];   // decoder_h [B,D]
    const float* key   = (const float*)d_in[1];   // key [B,L,A]
    // d_in[2] encoder_outputs — unused by the reference
    const float* prev  = (const float*)d_in[3];   // prev_att [B,L]
    const float* noise = (const float*)d_in[4];   // noise [B,L]
    const float* mask  = (const float*)d_in[5];   // mask [B,L]
    const float* W     = (const float*)d_in[6];   // W [A,D]
    const float* bias  = (const float*)d_in[7];   // b [A]
    const float* vw    = (const float*)d_in[8];   // v_weight [1,A]
    const float* vg    = (const float*)d_in[9];   // v_g [1]
    const float* vb    = (const float*)d_in[10];  // v_bias [1]
    const float* r     = (const float*)d_in[11];  // r [1]
    float* out = (float*)d_out;

    k_all<<<Bb, 512, 0, stream>>>(key, dh, W, bias, vw, vg, vb, r,
                                  noise, mask, prev, out);
}

// Round 13
// 39.770 us; speedup vs baseline: 1.9895x; 1.9895x over previous
//
#include <hip/hip_runtime.h>
#include <math.h>

#define Bb 64
#define Ll 1024
#define Dd 512
#define Aa 512
#define NEG_INF -1e9f

#define LOG2E  1.4426950408889634f
#define LOG2E2 2.8853901617526703f   // 2*log2(e)

typedef float fx4 __attribute__((ext_vector_type(4)));

__device__ __forceinline__ float fast_exp2(float x) { return __builtin_amdgcn_exp2f(x); }
__device__ __forceinline__ float fast_rcp(float x)  { return __builtin_amdgcn_rcpf(x); }

// 4-element partial: sum_j v[j] * rcp(exp2(k[j]*2log2e + qpre[j]) + 1)
#define TERM4(ACC, K, Q, V)                                                   \
    ACC = fmaf(V.x, fast_rcp(fast_exp2(fmaf(K.x, LOG2E2, Q.x)) + 1.f), ACC);  \
    ACC = fmaf(V.y, fast_rcp(fast_exp2(fmaf(K.y, LOG2E2, Q.y)) + 1.f), ACC);  \
    ACC = fmaf(V.z, fast_rcp(fast_exp2(fmaf(K.z, LOG2E2, Q.z)) + 1.f), ACC);  \
    ACC = fmaf(V.w, fast_rcp(fast_exp2(fmaf(K.w, LOG2E2, Q.w)) + 1.f), ACC);

#define RED16(A)                   \
    A += __shfl_xor(A, 1);         \
    A += __shfl_xor(A, 2);         \
    A += __shfl_xor(A, 4);         \
    A += __shfl_xor(A, 8);

// ---------------- K_A: partial energies, a-chunked ----------------
// grid (8, 64), 256 thr. Block = (a-chunk c, batch b): q-slice once, then
// stream key[b, :, c*64..+64] with 16 loads in flight; partials -> LDS ->
// one coalesced 4KB flush to pw[b][c][0..1023].
__global__ __launch_bounds__(256) void k_epart(const float* __restrict__ key,
                                               const float* __restrict__ dh,
                                               const float* __restrict__ W,
                                               const float* __restrict__ bias,
                                               const float* __restrict__ vw,
                                               const float* __restrict__ vg,
                                               float* __restrict__ pw) {
    const int c = blockIdx.x;            // a-chunk (64 wide)
    const int b = blockIdx.y;
    const int tid = threadIdx.x;
    const int wave = tid >> 6, lane = tid & 63;
    const int g = lane >> 4, sub = lane & 15;

    __shared__ float h[Dd];
    __shared__ float qs[64];
    __shared__ float vs[64];
    __shared__ float red[4];
    __shared__ float pl[Ll];

    ((float2*)h)[tid] = ((const float2*)(dh + (size_t)b * Dd))[tid];

    // ||v||^2 (redundant per block)
    {
        float w0 = vw[tid], w1 = vw[tid + 256];
        float s = fmaf(w0, w0, w1 * w1);
        #pragma unroll
        for (int off = 32; off; off >>= 1) s += __shfl_xor(s, off);
        if (lane == 0) red[wave] = s;
    }
    __syncthreads();
    const float inv = rsqrtf(red[0] + red[1] + red[2] + red[3]);
    const float g2i = 2.f * vg[0] * inv;

    // q for rows c*64 .. +63 (4 threads per row; R6 K1 body)
    {
        const int r = tid >> 2, quart = tid & 3;
        const int arow = c * 64 + r;
        const float4* Wr = (const float4*)(W + (size_t)arow * Dd + quart * 128);
        const float4* h4 = (const float4*)(h + quart * 128);
        float acc = 0.f;
        #pragma unroll 8
        for (int i = 0; i < 32; ++i) {
            float4 wq = Wr[i];
            float4 hv = h4[i];
            acc = fmaf(wq.x, hv.x, acc);
            acc = fmaf(wq.y, hv.y, acc);
            acc = fmaf(wq.z, hv.z, acc);
            acc = fmaf(wq.w, hv.w, acc);
        }
        acc += __shfl_xor(acc, 1);
        acc += __shfl_xor(acc, 2);
        if (quart == 0) {
            qs[r] = (acc + bias[arow]) * LOG2E2;   // pre-scaled
            vs[r] = g2i * vw[arow];                // = 2*vv
        }
    }
    __syncthreads();

    const fx4 q0 = ((const fx4*)qs)[sub];
    const fx4 v0 = ((const fx4*)vs)[sub];
    // lane's column slice: 16-lane group covers 256B contiguous per row
    const float* kbase = key + ((size_t)b * Ll) * Aa + c * 64 + sub * 4;

    #pragma unroll 1
    for (int it = 0; it < 4; ++it) {
        const int base = it * 256 + wave * 64 + g * 16;  // group's first row
        const float* kp = kbase + (size_t)base * Aa;
        fx4 k0 = *(const fx4*)(kp + 0 * Aa);
        fx4 k1 = *(const fx4*)(kp + 1 * Aa);
        fx4 k2 = *(const fx4*)(kp + 2 * Aa);
        fx4 k3 = *(const fx4*)(kp + 3 * Aa);
        fx4 k4 = *(const fx4*)(kp + 4 * Aa);
        fx4 k5 = *(const fx4*)(kp + 5 * Aa);
        fx4 k6 = *(const fx4*)(kp + 6 * Aa);
        fx4 k7 = *(const fx4*)(kp + 7 * Aa);
        fx4 k8 = *(const fx4*)(kp + 8 * Aa);
        fx4 k9 = *(const fx4*)(kp + 9 * Aa);
        fx4 kA = *(const fx4*)(kp + 10 * Aa);
        fx4 kB = *(const fx4*)(kp + 11 * Aa);
        fx4 kC = *(const fx4*)(kp + 12 * Aa);
        fx4 kD = *(const fx4*)(kp + 13 * Aa);
        fx4 kE = *(const fx4*)(kp + 14 * Aa);
        fx4 kF = *(const fx4*)(kp + 15 * Aa);
        __builtin_amdgcn_sched_barrier(0);   // keep 16 loads above compute

        float a0 = 0.f, a1 = 0.f, a2 = 0.f, a3 = 0.f,
              a4 = 0.f, a5 = 0.f, a6 = 0.f, a7 = 0.f,
              a8 = 0.f, a9 = 0.f, aA = 0.f, aB = 0.f,
              aC = 0.f, aD = 0.f, aE = 0.f, aF = 0.f;
        TERM4(a0, k0, q0, v0) TERM4(a1, k1, q0, v0)
        TERM4(a2, k2, q0, v0) TERM4(a3, k3, q0, v0)
        TERM4(a4, k4, q0, v0) TERM4(a5, k5, q0, v0)
        TERM4(a6, k6, q0, v0) TERM4(a7, k7, q0, v0)
        TERM4(a8, k8, q0, v0) TERM4(a9, k9, q0, v0)
        TERM4(aA, kA, q0, v0) TERM4(aB, kB, q0, v0)
        TERM4(aC, kC, q0, v0) TERM4(aD, kD, q0, v0)
        TERM4(aE, kE, q0, v0) TERM4(aF, kF, q0, v0)

        RED16(a0) RED16(a1) RED16(a2) RED16(a3)
        RED16(a4) RED16(a5) RED16(a6) RED16(a7)
        RED16(a8) RED16(a9) RED16(aA) RED16(aB)
        RED16(aC) RED16(aD) RED16(aE) RED16(aF)

        if (sub == 0) {
            pl[base + 0]  = a0; pl[base + 1]  = a1;
            pl[base + 2]  = a2; pl[base + 3]  = a3;
            pl[base + 4]  = a4; pl[base + 5]  = a5;
            pl[base + 6]  = a6; pl[base + 7]  = a7;
            pl[base + 8]  = a8; pl[base + 9]  = a9;
            pl[base + 10] = aA; pl[base + 11] = aB;
            pl[base + 12] = aC; pl[base + 13] = aD;
            pl[base + 14] = aE; pl[base + 15] = aF;
        }
        __builtin_amdgcn_sched_barrier(0);
    }
    __syncthreads();
    // coalesced flush: pw[b][c][0..1023]
    ((fx4*)(pw + ((size_t)b * 8 + c) * Ll))[tid] = ((const fx4*)pl)[tid];
}

// ---------------- K_B: reduce partials + sigmoid + scan ----------------
// grid (Bb), 256 thr. (R9's passed k_finish; gather is plane-strided now.)
__global__ __launch_bounds__(256) void k_finish(const float* __restrict__ pw,
                                                const float* __restrict__ noise,
                                                const float* __restrict__ mask,
                                                const float* __restrict__ prev,
                                                const float* __restrict__ vw,
                                                const float* __restrict__ vg,
                                                const float* __restrict__ vb,
                                                const float* __restrict__ r,
                                                float* __restrict__ alpha) {
    const int b = blockIdx.x;
    const int tid = threadIdx.x;
    const int wave = tid >> 6, lane = tid & 63;
    __shared__ float red[4], red2[4], pend[4], wA[4], wB[4];

    // ec = sum(vv) + vbias + r, redundant per block
    {
        float w0 = vw[tid], w1 = vw[tid + 256];
        float s = fmaf(w0, w0, w1 * w1);
        float t = w0 + w1;
        #pragma unroll
        for (int off = 32; off; off >>= 1) {
            s += __shfl_xor(s, off);
            t += __shfl_xor(t, off);
        }
        if (lane == 0) { red[wave] = s; red2[wave] = t; }
    }
    __syncthreads();
    const float inv = rsqrtf(red[0] + red[1] + red[2] + red[3]);
    const float sumv = red2[0] + red2[1] + red2[2] + red2[3];
    const float ec = vg[0] * inv * sumv + vb[0] + r[0];

    const int l0 = tid * 4;
    const float* pwb = pw + (size_t)b * 8 * Ll + l0;
    fx4 es = *(const fx4*)(pwb);
    es += *(const fx4*)(pwb + 1 * Ll);
    es += *(const fx4*)(pwb + 2 * Ll);
    es += *(const fx4*)(pwb + 3 * Ll);
    es += *(const fx4*)(pwb + 4 * Ll);
    es += *(const fx4*)(pwb + 5 * Ll);
    es += *(const fx4*)(pwb + 6 * Ll);
    es += *(const fx4*)(pwb + 7 * Ll);

    const float4 nz = ((const float4*)(noise + (size_t)b * Ll))[tid];
    const float4 mk = ((const float4*)(mask + (size_t)b * Ll))[tid];
    const float mk4 = (tid == 255) ? 0.f : mask[(size_t)b * Ll + l0 + 4];

    float4 pp;
    {
        float e, z, pv, em;
        e = (mk.x > 0.f) ? (ec - es.x) : NEG_INF; z = e + nz.x;
        pv = fast_rcp(1.f + fast_exp2(-z * LOG2E));
        em = mk.x * (1.f - mk.y); pp.x = (em > 0.f) ? em : pv;
        e = (mk.y > 0.f) ? (ec - es.y) : NEG_INF; z = e + nz.y;
        pv = fast_rcp(1.f + fast_exp2(-z * LOG2E));
        em = mk.y * (1.f - mk.z); pp.y = (em > 0.f) ? em : pv;
        e = (mk.z > 0.f) ? (ec - es.z) : NEG_INF; z = e + nz.z;
        pv = fast_rcp(1.f + fast_exp2(-z * LOG2E));
        em = mk.z * (1.f - mk.w); pp.z = (em > 0.f) ? em : pv;
        e = (mk.w > 0.f) ? (ec - es.w) : NEG_INF; z = e + nz.w;
        pv = fast_rcp(1.f + fast_exp2(-z * LOG2E));
        em = mk.w * (1.f - mk4); pp.w = (em > 0.f) ? em : pv;
    }

    if (lane == 63) pend[wave] = pp.w;
    __syncthreads();
    float pm1 = __shfl_up(pp.w, 1);
    if (lane == 0) pm1 = (wave == 0) ? 0.f : pend[wave - 1];

    const float4 pa = ((const float4*)(prev + (size_t)b * Ll))[tid];
    const float a0 = 1.f - pm1;
    const float a1 = 1.f - pp.x;
    const float a2 = 1.f - pp.y;
    const float a3 = 1.f - pp.z;

    float A = a0, Bv = pa.x;
    Bv = fmaf(a1, Bv, pa.y); A *= a1;
    Bv = fmaf(a2, Bv, pa.z); A *= a2;
    Bv = fmaf(a3, Bv, pa.w); A *= a3;

    float Ai = A, Bi = Bv;
    #pragma unroll
    for (int off = 1; off < 64; off <<= 1) {
        float qA = __shfl_up(Ai, off);
        float qB = __shfl_up(Bi, off);
        if (lane >= off) { Bi = fmaf(Ai, qB, Bi); Ai *= qA; }
    }
    float eA = __shfl_up(Ai, 1), eB = __shfl_up(Bi, 1);
    if (lane == 0) { eA = 1.f; eB = 0.f; }
    if (lane == 63) { wA[wave] = Ai; wB[wave] = Bi; }
    __syncthreads();
    float bwe = 0.f;
    for (int w2 = 0; w2 < wave; ++w2) bwe = fmaf(wA[w2], bwe, wB[w2]);
    float x = fmaf(eA, bwe, eB);

    float4 o;
    x = fmaf(a0, x, pa.x); o.x = pp.x * x;
    x = fmaf(a1, x, pa.y); o.y = pp.y * x;
    x = fmaf(a2, x, pa.z); o.z = pp.z * x;
    x = fmaf(a3, x, pa.w); o.w = pp.w * x;
    ((float4*)(alpha + (size_t)b * Ll))[tid] = o;
}

extern "C" void kernel_launch(void* const* d_in, const int* in_sizes, int n_in,
                              void* d_out, int out_size, void* d_ws, size_t ws_size,
                              hipStream_t stream) {
    const float* dh    = (const float*)d_in[0];   // decoder_h [B,D]
    const float* key   = (const float*)d_in[1];   // key [B,L,A]
    // d_in[2] encoder_outputs — unused by the reference
    const float* prev  = (const float*)d_in[3];   // prev_att [B,L]
    const float* noise = (const float*)d_in[4];   // noise [B,L]
    const float* mask  = (const float*)d_in[5];   // mask [B,L]
    const float* W     = (const float*)d_in[6];   // W [A,D]
    const float* bias  = (const float*)d_in[7];   // b [A]
    const float* vw    = (const float*)d_in[8];   // v_weight [1,A]
    const float* vg    = (const float*)d_in[9];   // v_g [1]
    const float* vb    = (const float*)d_in[10];  // v_bias [1]
    const float* r     = (const float*)d_in[11];  // r [1]
    float* out = (float*)d_out;

    float* pw = (float*)d_ws;                     // [64][8][1024] f32 = 2 MB

    k_epart<<<dim3(8, Bb), 256, 0, stream>>>(key, dh, W, bias, vw, vg, pw);
    k_finish<<<Bb, 256, 0, stream>>>(pw, noise, mask, prev, vw, vg, vb, r, out);
}